// Round 6
// baseline (1081.781 us; speedup 1.0000x reference)
//
#include <hip/hip_runtime.h>
#include <hip/hip_bf16.h>

typedef __attribute__((ext_vector_type(8))) short short8;
typedef __attribute__((ext_vector_type(4))) float f32x4;
typedef __attribute__((ext_vector_type(2))) unsigned int u32x2;

#define DIN  4096
#define DOUT 4096
#define NTOK 16384

static __device__ __forceinline__ unsigned short f2b(float f) {
  union { __hip_bfloat16 h; unsigned short u; } cv;
  cv.h = __float2bfloat16(f);
  return cv.u;
}

static __device__ __forceinline__ short8 pack8(float4 f0, float4 f1) {
  short8 s;
  s[0] = (short)f2b(f0.x); s[1] = (short)f2b(f0.y);
  s[2] = (short)f2b(f0.z); s[3] = (short)f2b(f0.w);
  s[4] = (short)f2b(f1.x); s[5] = (short)f2b(f1.y);
  s[6] = (short)f2b(f1.z); s[7] = (short)f2b(f1.w);
  return s;
}

// ------------- prologue (merged): transpose+convert weights to bf16 ----------
// btt_r[n][b][k] f32 -> Rt[n][c=k][b] bf16 ; btt_l[m][j][a] f32 -> Lt[m][a][j]
__global__ __launch_bounds__(256) void prep(const float* __restrict__ r,
                                            const float* __restrict__ l,
                                            unsigned short* __restrict__ rt,
                                            unsigned short* __restrict__ lt) {
  __shared__ unsigned short tile[128 * 68];
  const int q = threadIdx.x;
  if (blockIdx.x < 64) {
    const int n = blockIdx.x;
#pragma unroll
    for (int it = 0; it < 8; ++it) {
      const int idx = q + it * 256;           // float4 units
      const int b = idx >> 5, k4 = idx & 31;
      const float4 v = *(const float4*)(r + (size_t)n * 8192 + b * 128 + k4 * 4);
      unsigned int lo = (unsigned)f2b(v.x) | ((unsigned)f2b(v.y) << 16);
      unsigned int hi = (unsigned)f2b(v.z) | ((unsigned)f2b(v.w) << 16);
      u32x2 pk = {lo, hi};
      *(u32x2*)((char*)tile + (b * 264 + k4 * 8)) = pk;   // [b][k] stride 132
    }
    __syncthreads();
#pragma unroll
    for (int it = 0; it < 32; ++it) {
      const int o = q + it * 256;             // o = c*64 + b
      const int c = o >> 6, b = o & 63;
      rt[(size_t)n * 8192 + o] = tile[b * 132 + c];
    }
  } else {
    const int m = blockIdx.x - 64;
#pragma unroll
    for (int it = 0; it < 8; ++it) {
      const int idx = q + it * 256;
      const int j = idx >> 4, a4 = idx & 15;
      const float4 v = *(const float4*)(l + (size_t)m * 8192 + j * 64 + a4 * 4);
      unsigned int lo = (unsigned)f2b(v.x) | ((unsigned)f2b(v.y) << 16);
      unsigned int hi = (unsigned)f2b(v.z) | ((unsigned)f2b(v.w) << 16);
      u32x2 pk = {lo, hi};
      *(u32x2*)((char*)tile + (j * 136 + a4 * 8)) = pk;   // [j][a] stride 68
    }
    __syncthreads();
#pragma unroll
    for (int it = 0; it < 32; ++it) {
      const int o = q + it * 256;             // o = a*128 + j
      const int a = o >> 7, j = o & 127;
      lt[(size_t)m * 8192 + o] = tile[j * 68 + a];
    }
  }
}

// ---------------- fused kernel v2: 16 waves, 2 blocks/CU, Lt prefetched ------
// block = 16 tokens, 16 waves. 4 groups of 16 n.
// stage1: wave w computes n = g*16 + w -> LDS h[nl=w][m][t][r], 2-way swizzle
// stage2: wave w owns m in [4w, 4w+4); B-frag from LDS, A-frag (Lt) PRE-LOADED
//         into regs before STAGE1 -> no global load after any barrier.
// barriers: lgkmcnt(0) + s_barrier (vmcnt NOT drained -> prefetches survive)
__global__ __launch_bounds__(1024, 8) void fused(const float* __restrict__ x,
                                                 const unsigned short* __restrict__ rt,
                                                 const unsigned short* __restrict__ lt,
                                                 const float* __restrict__ bias,
                                                 float* __restrict__ y) {
  __shared__ unsigned short hlds[32768];      // 64 KB: [16 nl][64 m][16 t][2 r]
  const int t0 = blockIdx.x * 16;
  const int tid = threadIdx.x, w = tid >> 6, lane = tid & 63;
  const int l15 = lane & 15, l4 = lane >> 4;

  const float* xrow = x + (size_t)(t0 + l15) * DIN + l4 * 8;

  f32x4 acc[4][4];
#pragma unroll
  for (int mi = 0; mi < 4; ++mi)
#pragma unroll
    for (int at = 0; at < 4; ++at) acc[mi][at] = (f32x4){0.f, 0.f, 0.f, 0.f};

  float4 xA[2][2], xB[2][2];                  // [ks][half] x prefetch
  short8 lf[4][4];                            // Lt prefetch [mi][at]

  auto LOADX = [&](int g, float4 (&xb)[2][2]) {
    const float* p = xrow + (size_t)(g * 16 + w) * 64;
#pragma unroll
    for (int ks = 0; ks < 2; ++ks)
#pragma unroll
      for (int h = 0; h < 2; ++h)
        xb[ks][h] = *(const float4*)(p + ks * 32 + h * 4);
  };

  auto LOADL = [&](int g) {
#pragma unroll
    for (int mi = 0; mi < 4; ++mi) {
      const unsigned short* lb =
          lt + (size_t)(w * 4 + mi) * 8192 + l15 * 128 + g * 32 + l4 * 8;
#pragma unroll
      for (int at = 0; at < 4; ++at)
        lf[mi][at] = *(const short8*)(lb + at * 2048);
    }
  };

  auto STAGE1 = [&](int g, float4 (&xb)[2][2]) {
    const int n = g * 16 + w;
    const short8 xf0 = pack8(xb[0][0], xb[0][1]);
    const short8 xf1 = pack8(xb[1][0], xb[1][1]);
    const unsigned short* rb = rt + (size_t)n * 8192 + l15 * 64 + l4 * 8;
#pragma unroll
    for (int ct = 0; ct < 8; ++ct) {
      const short8 r0 = *(const short8*)(rb + ct * 1024);
      const short8 r1 = *(const short8*)(rb + ct * 1024 + 32);
      f32x4 s = {0.f, 0.f, 0.f, 0.f};
      s = __builtin_amdgcn_mfma_f32_16x16x32_bf16(r0, xf0, s, 0, 0, 0);
      s = __builtin_amdgcn_mfma_f32_16x16x32_bf16(r1, xf1, s, 0, 0, 0);
      // D: row = c = ct*16 + l4*4 + jj (c = m*2+r), col = t = l15
      const int m0 = ct * 8 + l4 * 2;
#pragma unroll
      for (int dd = 0; dd < 2; ++dd) {
        const int m = m0 + dd;
        const unsigned int pk =
            (unsigned)f2b(s[2 * dd]) | ((unsigned)f2b(s[2 * dd + 1]) << 16);
        int byte = w * 4096 + m * 64 + l15 * 4;
        byte ^= ((((m >> 1) ^ (w >> 2)) & 1) << 6);
        *(unsigned int*)((char*)hlds + byte) = pk;
      }
    }
  };

  auto STAGE2 = [&]() {
#pragma unroll
    for (int mi = 0; mi < 4; ++mi) {
      const int m = w * 4 + mi;
      union { unsigned int u[4]; short8 s; } hu;
#pragma unroll
      for (int q = 0; q < 4; ++q) {
        const int nl = l4 * 4 + q;
        int byte = nl * 4096 + m * 64 + l15 * 4;
        byte ^= ((((m >> 1) ^ (nl >> 2)) & 1) << 6);
        hu.u[q] = *(const unsigned int*)((char*)hlds + byte);
      }
#pragma unroll
      for (int at = 0; at < 4; ++at)
        acc[mi][at] =
            __builtin_amdgcn_mfma_f32_16x16x32_bf16(lf[mi][at], hu.s, acc[mi][at], 0, 0, 0);
    }
  };

#define BARRIER()                                          \
  do {                                                     \
    asm volatile("s_waitcnt lgkmcnt(0)" ::: "memory");     \
    __builtin_amdgcn_s_barrier();                          \
    asm volatile("" ::: "memory");                         \
  } while (0)

  LOADX(0, xA);
  LOADL(0); LOADX(1, xB); STAGE1(0, xA); BARRIER(); STAGE2(); BARRIER();
  LOADL(1); LOADX(2, xA); STAGE1(1, xB); BARRIER(); STAGE2(); BARRIER();
  LOADL(2); LOADX(3, xB); STAGE1(2, xA); BARRIER(); STAGE2(); BARRIER();
  LOADL(3);               STAGE1(3, xB); BARRIER(); STAGE2();

  // epilogue: y = acc + bias, float4 stores
#pragma unroll
  for (int mi = 0; mi < 4; ++mi) {
    const int m = w * 4 + mi;
    float* yb = y + (size_t)(t0 + l15) * DOUT + m * 64 + l4 * 4;
    const float* bb = bias + m * 64 + l4 * 4;
#pragma unroll
    for (int at = 0; at < 4; ++at) {
      const float4 bv = *(const float4*)(bb + at * 16);
      float4 o;
      o.x = acc[mi][at][0] + bv.x;
      o.y = acc[mi][at][1] + bv.y;
      o.z = acc[mi][at][2] + bv.z;
      o.w = acc[mi][at][3] + bv.w;
      *(float4*)(yb + at * 16) = o;
    }
  }
#undef BARRIER
}

extern "C" void kernel_launch(void* const* d_in, const int* in_sizes, int n_in,
                              void* d_out, int out_size, void* d_ws, size_t ws_size,
                              hipStream_t stream) {
  const float* x    = (const float*)d_in[0];
  const float* bl   = (const float*)d_in[1];
  const float* br   = (const float*)d_in[2];
  const float* bias = (const float*)d_in[3];
  float* y = (float*)d_out;

  unsigned short* rt  = (unsigned short*)d_ws;           // 1 MB
  unsigned short* ltw = rt + 64 * 8192;                  // 1 MB

  prep<<<128, 256, 0, stream>>>(br, bl, rt, ltw);
  fused<<<NTOK / 16, 1024, 0, stream>>>(x, rt, ltw, bias, y);
}

// Round 7
// 347.711 us; speedup vs baseline: 3.1112x; 3.1112x over previous
//
#include <hip/hip_runtime.h>
#include <hip/hip_bf16.h>

typedef __attribute__((ext_vector_type(8))) short short8;
typedef __attribute__((ext_vector_type(4))) float f32x4;
typedef __attribute__((ext_vector_type(4))) unsigned int u32x4;
typedef __attribute__((ext_vector_type(2))) unsigned int u32x2;

#define DIN  4096
#define DOUT 4096
#define NTOK 16384

static __device__ __forceinline__ unsigned short f2b(float f) {
  union { __hip_bfloat16 h; unsigned short u; } cv;
  cv.h = __float2bfloat16(f);
  return cv.u;
}

static __device__ __forceinline__ short8 pack8(float4 f0, float4 f1) {
  short8 s;
  s[0] = (short)f2b(f0.x); s[1] = (short)f2b(f0.y);
  s[2] = (short)f2b(f0.z); s[3] = (short)f2b(f0.w);
  s[4] = (short)f2b(f1.x); s[5] = (short)f2b(f1.y);
  s[6] = (short)f2b(f1.z); s[7] = (short)f2b(f1.w);
  return s;
}

// ------------- prologue (merged): transpose+convert weights to bf16 ----------
// btt_r[n][b][k] f32 -> Rt[n][c=k][b] bf16 ; btt_l[m][j][a] f32 -> Lt[m][a][j]
__global__ __launch_bounds__(256) void prep(const float* __restrict__ r,
                                            const float* __restrict__ l,
                                            unsigned short* __restrict__ rt,
                                            unsigned short* __restrict__ lt) {
  __shared__ unsigned short tile[128 * 68];
  const int q = threadIdx.x;
  if (blockIdx.x < 64) {
    const int n = blockIdx.x;
#pragma unroll
    for (int it = 0; it < 8; ++it) {
      const int idx = q + it * 256;           // float4 units
      const int b = idx >> 5, k4 = idx & 31;
      const float4 v = *(const float4*)(r + (size_t)n * 8192 + b * 128 + k4 * 4);
      unsigned int lo = (unsigned)f2b(v.x) | ((unsigned)f2b(v.y) << 16);
      unsigned int hi = (unsigned)f2b(v.z) | ((unsigned)f2b(v.w) << 16);
      u32x2 pk = {lo, hi};
      *(u32x2*)((char*)tile + (b * 264 + k4 * 8)) = pk;   // [b][k] stride 132
    }
    __syncthreads();
#pragma unroll
    for (int it = 0; it < 32; ++it) {
      const int o = q + it * 256;             // o = c*64 + b
      const int c = o >> 6, b = o & 63;
      rt[(size_t)n * 8192 + o] = tile[b * 132 + c];
    }
  } else {
    const int m = blockIdx.x - 64;
#pragma unroll
    for (int it = 0; it < 8; ++it) {
      const int idx = q + it * 256;
      const int j = idx >> 4, a4 = idx & 15;
      const float4 v = *(const float4*)(l + (size_t)m * 8192 + j * 64 + a4 * 4);
      unsigned int lo = (unsigned)f2b(v.x) | ((unsigned)f2b(v.y) << 16);
      unsigned int hi = (unsigned)f2b(v.z) | ((unsigned)f2b(v.w) << 16);
      u32x2 pk = {lo, hi};
      *(u32x2*)((char*)tile + (j * 136 + a4 * 8)) = pk;   // [j][a] stride 68
    }
    __syncthreads();
#pragma unroll
    for (int it = 0; it < 32; ++it) {
      const int o = q + it * 256;             // o = a*128 + j
      const int a = o >> 7, j = o & 127;
      lt[(size_t)m * 8192 + o] = tile[j * 68 + a];
    }
  }
}

// ---------------- kernel1: stage1, un-chunked, long-loop streaming -----------
// h layout: [tile16][n][c][t&15] bf16, tile16 = 0..1023
// grid (32 strips, 64 n); block 256 = 4 waves; strip = 512 tokens;
// wave loops 8 tile16s with 1-deep register prefetch. No barriers.
__global__ __launch_bounds__(256, 4) void k1(const float* __restrict__ x,
                                             const unsigned short* __restrict__ rt,
                                             unsigned short* __restrict__ hbuf) {
  const int n = blockIdx.y;
  const int strip = blockIdx.x;
  const int wave = threadIdx.x >> 6, lane = threadIdx.x & 63;
  const int l15 = lane & 15, l4 = lane >> 4;

  // B-fragments register-resident: Rt[n][c=ct*16+l15][b=ks*32+l4*8 ..+8]
  short8 bf[8][2];
  {
    const unsigned short* rbase = rt + (size_t)n * 8192 + l15 * 64 + l4 * 8;
#pragma unroll
    for (int ct = 0; ct < 8; ++ct)
#pragma unroll
      for (int ks = 0; ks < 2; ++ks)
        bf[ct][ks] = *(const short8*)(rbase + ct * 1024 + ks * 32);
  }

  const float* xb = x + (size_t)(strip * 512 + wave * 16 + l15) * DIN + n * 64 + l4 * 8;
  const size_t itstride = (size_t)64 * DIN;           // 64 tokens per iteration

  float4 p0[4], p1[4];
  p0[0] = *(const float4*)(xb);      p0[1] = *(const float4*)(xb + 4);
  p0[2] = *(const float4*)(xb + 32); p0[3] = *(const float4*)(xb + 36);
#pragma unroll
  for (int it = 0; it < 8; ++it) {
    if (it < 7) {
      const float* xn = xb + (size_t)(it + 1) * itstride;
      float4* dst = (it & 1) ? p0 : p1;
      dst[0] = *(const float4*)(xn);      dst[1] = *(const float4*)(xn + 4);
      dst[2] = *(const float4*)(xn + 32); dst[3] = *(const float4*)(xn + 36);
    }
    const float4* cur = (it & 1) ? p1 : p0;
    const short8 a0 = pack8(cur[0], cur[1]);          // b-slice 0..31
    const short8 a1 = pack8(cur[2], cur[3]);          // b-slice 32..63
    const int tile = strip * 32 + it * 4 + wave;
    unsigned short* hb = hbuf + (size_t)(tile * 64 + n) * 2048 + l15 * 16 + l4 * 4;
#pragma unroll
    for (int ct = 0; ct < 8; ++ct) {
      f32x4 acc = {0.f, 0.f, 0.f, 0.f};
      acc = __builtin_amdgcn_mfma_f32_16x16x32_bf16(a0, bf[ct][0], acc, 0, 0, 0);
      acc = __builtin_amdgcn_mfma_f32_16x16x32_bf16(a1, bf[ct][1], acc, 0, 0, 0);
      // D: col = c = ct*16+l15, row = t = l4*4 + reg
      unsigned int lo = (unsigned)f2b(acc[0]) | ((unsigned)f2b(acc[1]) << 16);
      unsigned int hi = (unsigned)f2b(acc[2]) | ((unsigned)f2b(acc[3]) << 16);
      u32x2 pk = {lo, hi};
      *(u32x2*)(hb + ct * 256) = pk;                  // 512B contiguous per wave
    }
  }
}

// ---------------- kernel2: stage2, un-chunked, m-paired, dbuf ----------------
// block owns m-pair mp -> c in {4mp..4mp+3} = full 128B line per (tile,n)
// grid (32 strips, 32 mp); block 256 = 4 waves; strip = 512 tokens = 16 iters
__global__ __launch_bounds__(256) void k2(const unsigned short* __restrict__ hbuf,
                                          const unsigned short* __restrict__ lt,
                                          const float* __restrict__ bias,
                                          float* __restrict__ y) {
  __shared__ unsigned short as_[2][2][32 * 128];  // [buf][m_loc][t][j] swizzled
  const int mp = blockIdx.y;
  const int strip = blockIdx.x;
  const int tid = threadIdx.x;
  const int wave = tid >> 6, lane = tid & 63;
  const int l15 = lane & 15, l4 = lane >> 4;
  const int m_loc = wave & 1, ah = wave >> 1;
  const int m = mp * 2 + m_loc;

  // B-fragments: Lt[m][a][j=ks*32+l4*8..+8], a = ah*32 + at*16 + l15
  short8 bfr[2][4];
#pragma unroll
  for (int at = 0; at < 2; ++at)
#pragma unroll
    for (int ks = 0; ks < 4; ++ks)
      bfr[at][ks] = *(const short8*)(lt + (size_t)m * 8192 +
                      (ah * 32 + at * 16 + l15) * 128 + ks * 32 + l4 * 8);
  const float bv0 = bias[m * 64 + ah * 32 + l15];
  const float bv1 = bias[m * 64 + ah * 32 + 16 + l15];

  auto stage = [&](int it, int b) {
#pragma unroll
    for (int half = 0; half < 4; ++half) {
      const int idx = tid + half * 256;           // 0..1023 16B units
      const int sub8 = idx & 7, nn = (idx >> 3) & 63, tio = idx >> 9;
      const int tg16 = strip * 32 + it * 2 + tio;
      const u32x4 v = *(const u32x4*)(hbuf + (size_t)(tg16 * 64 + nn) * 2048 +
                                      mp * 64 + sub8 * 8);
      const int c_loc = sub8 >> 1, hh = sub8 & 1;
      const int j = nn * 2 + (c_loc & 1), ml = c_loc >> 1;
      char* base = (char*)as_ + ((b * 2 + ml) * 32) * 256;
#pragma unroll
      for (int e = 0; e < 8; ++e) {
        const unsigned int w = v[e >> 1];
        const unsigned short val = (e & 1) ? (unsigned short)(w >> 16)
                                           : (unsigned short)(w & 0xffff);
        const int t = tio * 16 + hh * 8 + e;
        *(unsigned short*)(base + t * 256 + ((j * 2) ^ ((t & 7) << 4))) = val;
      }
    }
  };

  stage(0, 0);
  __syncthreads();
  int buf = 0;
  for (int it = 0; it < 16; ++it) {
    if (it < 15) stage(it + 1, buf ^ 1);
    f32x4 acc00 = {0,0,0,0}, acc01 = {0,0,0,0}, acc10 = {0,0,0,0}, acc11 = {0,0,0,0};
    const char* abase = (char*)as_ + ((buf * 2 + m_loc) * 32) * 256;
#pragma unroll
    for (int th = 0; th < 2; ++th) {
      const int t = th * 16 + l15;
#pragma unroll
      for (int ks = 0; ks < 4; ++ks) {
        const short8 av = *(const short8*)(abase + t * 256 +
                            ((ks * 64 + l4 * 16) ^ ((t & 7) << 4)));
        if (th == 0) {
          acc00 = __builtin_amdgcn_mfma_f32_16x16x32_bf16(av, bfr[0][ks], acc00, 0, 0, 0);
          acc10 = __builtin_amdgcn_mfma_f32_16x16x32_bf16(av, bfr[1][ks], acc10, 0, 0, 0);
        } else {
          acc01 = __builtin_amdgcn_mfma_f32_16x16x32_bf16(av, bfr[0][ks], acc01, 0, 0, 0);
          acc11 = __builtin_amdgcn_mfma_f32_16x16x32_bf16(av, bfr[1][ks], acc11, 0, 0, 0);
        }
      }
    }
    const size_t t0 = (size_t)(strip * 512 + it * 32 + l4 * 4);
    float* y0 = y + (size_t)m * 64 + ah * 32 + l15;
#pragma unroll
    for (int jj = 0; jj < 4; ++jj) {
      y0[(t0 + jj) * DOUT]      = acc00[jj] + bv0;
      y0[(t0 + jj) * DOUT + 16] = acc10[jj] + bv1;
      y0[(t0 + 16 + jj) * DOUT]      = acc01[jj] + bv0;
      y0[(t0 + 16 + jj) * DOUT + 16] = acc11[jj] + bv1;
    }
    __syncthreads();
    buf ^= 1;
  }
}

extern "C" void kernel_launch(void* const* d_in, const int* in_sizes, int n_in,
                              void* d_out, int out_size, void* d_ws, size_t ws_size,
                              hipStream_t stream) {
  const float* x    = (const float*)d_in[0];
  const float* bl   = (const float*)d_in[1];
  const float* br   = (const float*)d_in[2];
  const float* bias = (const float*)d_in[3];
  float* y = (float*)d_out;

  unsigned short* rt   = (unsigned short*)d_ws;          // 1 MB
  unsigned short* ltw  = rt + 64 * 8192;                 // 1 MB
  unsigned short* hbuf = ltw + 64 * 8192;                // 268 MB

  prep<<<128, 256, 0, stream>>>(br, bl, rt, ltw);
  k1<<<dim3(32, 64), 256, 0, stream>>>(x, rt, hbuf);
  k2<<<dim3(32, 32), 256, 0, stream>>>(hbuf, ltw, bias, y);
}

// Round 8
// 265.731 us; speedup vs baseline: 4.0710x; 1.3085x over previous
//
#include <hip/hip_runtime.h>
#include <hip/hip_bf16.h>

typedef __attribute__((ext_vector_type(8))) short short8;
typedef __attribute__((ext_vector_type(4))) float f32x4;
typedef __attribute__((ext_vector_type(4))) unsigned int u32x4;
typedef __attribute__((ext_vector_type(2))) unsigned int u32x2;

#define DIN  4096
#define DOUT 4096
#define NTOK 16384

static __device__ __forceinline__ unsigned short f2b(float f) {
  union { __hip_bfloat16 h; unsigned short u; } cv;
  cv.h = __float2bfloat16(f);
  return cv.u;
}

static __device__ __forceinline__ short8 pack8(float4 f0, float4 f1) {
  short8 s;
  s[0] = (short)f2b(f0.x); s[1] = (short)f2b(f0.y);
  s[2] = (short)f2b(f0.z); s[3] = (short)f2b(f0.w);
  s[4] = (short)f2b(f1.x); s[5] = (short)f2b(f1.y);
  s[6] = (short)f2b(f1.z); s[7] = (short)f2b(f1.w);
  return s;
}

// ------------- prologue (merged): transpose+convert weights to bf16 ----------
// btt_r[n][b][k] f32 -> Rt[n][c=k][b] bf16 ; btt_l[m][j][a] f32 -> Lt[m][a][j]
__global__ __launch_bounds__(256) void prep(const float* __restrict__ r,
                                            const float* __restrict__ l,
                                            unsigned short* __restrict__ rt,
                                            unsigned short* __restrict__ lt) {
  __shared__ unsigned short tile[128 * 68];
  const int q = threadIdx.x;
  if (blockIdx.x < 64) {
    const int n = blockIdx.x;
#pragma unroll
    for (int it = 0; it < 8; ++it) {
      const int idx = q + it * 256;           // float4 units
      const int b = idx >> 5, k4 = idx & 31;
      const float4 v = *(const float4*)(r + (size_t)n * 8192 + b * 128 + k4 * 4);
      unsigned int lo = (unsigned)f2b(v.x) | ((unsigned)f2b(v.y) << 16);
      unsigned int hi = (unsigned)f2b(v.z) | ((unsigned)f2b(v.w) << 16);
      u32x2 pk = {lo, hi};
      *(u32x2*)((char*)tile + (b * 264 + k4 * 8)) = pk;   // [b][k] stride 132
    }
    __syncthreads();
#pragma unroll
    for (int it = 0; it < 32; ++it) {
      const int o = q + it * 256;             // o = c*64 + b
      const int c = o >> 6, b = o & 63;
      rt[(size_t)n * 8192 + o] = tile[b * 132 + c];
    }
  } else {
    const int m = blockIdx.x - 64;
#pragma unroll
    for (int it = 0; it < 8; ++it) {
      const int idx = q + it * 256;
      const int j = idx >> 4, a4 = idx & 15;
      const float4 v = *(const float4*)(l + (size_t)m * 8192 + j * 64 + a4 * 4);
      unsigned int lo = (unsigned)f2b(v.x) | ((unsigned)f2b(v.y) << 16);
      unsigned int hi = (unsigned)f2b(v.z) | ((unsigned)f2b(v.w) << 16);
      u32x2 pk = {lo, hi};
      *(u32x2*)((char*)tile + (j * 136 + a4 * 8)) = pk;   // [j][a] stride 68
    }
    __syncthreads();
#pragma unroll
    for (int it = 0; it < 32; ++it) {
      const int o = q + it * 256;             // o = a*128 + j
      const int a = o >> 7, j = o & 127;
      lt[(size_t)m * 8192 + o] = tile[j * 68 + a];
    }
  }
}

// ---------------- kernel1: stage1, register-resident 3-buffer pipeline -------
// h layout: [tile16][n][c][t&15] bf16, tile16 = 0..1023
// grid (32 strips, 64 n); block 256 = 4 waves; strip = 512 tokens;
// wave loops 8 tile16s. NAMED buffers only (no arrays/pointer selects ->
// everything in VGPRs; prefetch distance = 2 compute phases). No barriers.
__global__ __launch_bounds__(256, 3) void k1(const float* __restrict__ x,
                                             const unsigned short* __restrict__ rt,
                                             unsigned short* __restrict__ hbuf) {
  const int n = blockIdx.y;
  const int strip = blockIdx.x;
  const int wave = threadIdx.x >> 6, lane = threadIdx.x & 63;
  const int l15 = lane & 15, l4 = lane >> 4;

  // B-fragments register-resident: Rt[n][c=ct*16+l15][b=ks*32+l4*8 ..+8]
  short8 bf[8][2];
  {
    const unsigned short* rbase = rt + (size_t)n * 8192 + l15 * 64 + l4 * 8;
#pragma unroll
    for (int ct = 0; ct < 8; ++ct)
#pragma unroll
      for (int ks = 0; ks < 2; ++ks)
        bf[ct][ks] = *(const short8*)(rbase + ct * 1024 + ks * 32);
  }

  const float* xb = x + (size_t)(strip * 512 + wave * 16 + l15) * DIN + n * 64 + l4 * 8;
  const size_t its = (size_t)64 * DIN;                // 64 tokens per tile step

  float4 A0, A1, A2, A3, B0, B1, B2, B3, C0, C1, C2, C3;

#define LOADT(P, i)                                        \
  {                                                        \
    const float* _p = xb + (size_t)(i) * its;              \
    P##0 = *(const float4*)(_p);                           \
    P##1 = *(const float4*)(_p + 4);                       \
    P##2 = *(const float4*)(_p + 32);                      \
    P##3 = *(const float4*)(_p + 36);                      \
  }

#define COMP(P, i)                                                          \
  {                                                                         \
    const short8 _a0 = pack8(P##0, P##1);                                   \
    const short8 _a1 = pack8(P##2, P##3);                                   \
    unsigned short* _hb = hbuf +                                            \
        (size_t)((strip * 32 + (i) * 4 + wave) * 64 + n) * 2048 +           \
        l15 * 16 + l4 * 4;                                                  \
    _Pragma("unroll")                                                       \
    for (int ct = 0; ct < 8; ++ct) {                                        \
      f32x4 _acc = {0.f, 0.f, 0.f, 0.f};                                    \
      _acc = __builtin_amdgcn_mfma_f32_16x16x32_bf16(_a0, bf[ct][0], _acc, 0, 0, 0); \
      _acc = __builtin_amdgcn_mfma_f32_16x16x32_bf16(_a1, bf[ct][1], _acc, 0, 0, 0); \
      unsigned int _lo = (unsigned)f2b(_acc[0]) | ((unsigned)f2b(_acc[1]) << 16);    \
      unsigned int _hi = (unsigned)f2b(_acc[2]) | ((unsigned)f2b(_acc[3]) << 16);    \
      u32x2 _pk = {_lo, _hi};                                               \
      *(u32x2*)(_hb + ct * 256) = _pk;                                      \
    }                                                                       \
  }

  LOADT(A, 0)
  LOADT(B, 1)
  LOADT(C, 2)
  COMP(A, 0) LOADT(A, 3)
  COMP(B, 1) LOADT(B, 4)
  COMP(C, 2) LOADT(C, 5)
  COMP(A, 3) LOADT(A, 6)
  COMP(B, 4) LOADT(B, 7)
  COMP(C, 5)
  COMP(A, 6)
  COMP(B, 7)

#undef LOADT
#undef COMP
}

// ---------------- kernel2: stage2, un-chunked, m-paired, dbuf ----------------
// block owns m-pair mp -> c in {4mp..4mp+3} = full 128B line per (tile,n)
// grid (32 strips, 32 mp); block 256 = 4 waves; strip = 512 tokens = 16 iters
__global__ __launch_bounds__(256) void k2(const unsigned short* __restrict__ hbuf,
                                          const unsigned short* __restrict__ lt,
                                          const float* __restrict__ bias,
                                          float* __restrict__ y) {
  __shared__ unsigned short as_[2][2][32 * 128];  // [buf][m_loc][t][j] swizzled
  const int mp = blockIdx.y;
  const int strip = blockIdx.x;
  const int tid = threadIdx.x;
  const int wave = tid >> 6, lane = tid & 63;
  const int l15 = lane & 15, l4 = lane >> 4;
  const int m_loc = wave & 1, ah = wave >> 1;
  const int m = mp * 2 + m_loc;

  // B-fragments: Lt[m][a][j=ks*32+l4*8..+8], a = ah*32 + at*16 + l15
  short8 bfr[2][4];
#pragma unroll
  for (int at = 0; at < 2; ++at)
#pragma unroll
    for (int ks = 0; ks < 4; ++ks)
      bfr[at][ks] = *(const short8*)(lt + (size_t)m * 8192 +
                      (ah * 32 + at * 16 + l15) * 128 + ks * 32 + l4 * 8);
  const float bv0 = bias[m * 64 + ah * 32 + l15];
  const float bv1 = bias[m * 64 + ah * 32 + 16 + l15];

  auto stage = [&](int it, int b) {
#pragma unroll
    for (int half = 0; half < 4; ++half) {
      const int idx = tid + half * 256;           // 0..1023 16B units
      const int sub8 = idx & 7, nn = (idx >> 3) & 63, tio = idx >> 9;
      const int tg16 = strip * 32 + it * 2 + tio;
      const u32x4 v = *(const u32x4*)(hbuf + (size_t)(tg16 * 64 + nn) * 2048 +
                                      mp * 64 + sub8 * 8);
      const int c_loc = sub8 >> 1, hh = sub8 & 1;
      const int j = nn * 2 + (c_loc & 1), ml = c_loc >> 1;
      char* base = (char*)as_ + ((b * 2 + ml) * 32) * 256;
#pragma unroll
      for (int e = 0; e < 8; ++e) {
        const unsigned int w = v[e >> 1];
        const unsigned short val = (e & 1) ? (unsigned short)(w >> 16)
                                           : (unsigned short)(w & 0xffff);
        const int t = tio * 16 + hh * 8 + e;
        *(unsigned short*)(base + t * 256 + ((j * 2) ^ ((t & 7) << 4))) = val;
      }
    }
  };

  stage(0, 0);
  __syncthreads();
  int buf = 0;
  for (int it = 0; it < 16; ++it) {
    if (it < 15) stage(it + 1, buf ^ 1);
    f32x4 acc00 = {0,0,0,0}, acc01 = {0,0,0,0}, acc10 = {0,0,0,0}, acc11 = {0,0,0,0};
    const char* abase = (char*)as_ + ((buf * 2 + m_loc) * 32) * 256;
#pragma unroll
    for (int th = 0; th < 2; ++th) {
      const int t = th * 16 + l15;
#pragma unroll
      for (int ks = 0; ks < 4; ++ks) {
        const short8 av = *(const short8*)(abase + t * 256 +
                            ((ks * 64 + l4 * 16) ^ ((t & 7) << 4)));
        if (th == 0) {
          acc00 = __builtin_amdgcn_mfma_f32_16x16x32_bf16(av, bfr[0][ks], acc00, 0, 0, 0);
          acc10 = __builtin_amdgcn_mfma_f32_16x16x32_bf16(av, bfr[1][ks], acc10, 0, 0, 0);
        } else {
          acc01 = __builtin_amdgcn_mfma_f32_16x16x32_bf16(av, bfr[0][ks], acc01, 0, 0, 0);
          acc11 = __builtin_amdgcn_mfma_f32_16x16x32_bf16(av, bfr[1][ks], acc11, 0, 0, 0);
        }
      }
    }
    const size_t t0 = (size_t)(strip * 512 + it * 32 + l4 * 4);
    float* y0 = y + (size_t)m * 64 + ah * 32 + l15;
#pragma unroll
    for (int jj = 0; jj < 4; ++jj) {
      y0[(t0 + jj) * DOUT]      = acc00[jj] + bv0;
      y0[(t0 + jj) * DOUT + 16] = acc10[jj] + bv1;
      y0[(t0 + 16 + jj) * DOUT]      = acc01[jj] + bv0;
      y0[(t0 + 16 + jj) * DOUT + 16] = acc11[jj] + bv1;
    }
    __syncthreads();
    buf ^= 1;
  }
}

extern "C" void kernel_launch(void* const* d_in, const int* in_sizes, int n_in,
                              void* d_out, int out_size, void* d_ws, size_t ws_size,
                              hipStream_t stream) {
  const float* x    = (const float*)d_in[0];
  const float* bl   = (const float*)d_in[1];
  const float* br   = (const float*)d_in[2];
  const float* bias = (const float*)d_in[3];
  float* y = (float*)d_out;

  unsigned short* rt   = (unsigned short*)d_ws;          // 1 MB
  unsigned short* ltw  = rt + 64 * 8192;                 // 1 MB
  unsigned short* hbuf = ltw + 64 * 8192;                // 268 MB

  prep<<<128, 256, 0, stream>>>(br, bl, rt, ltw);
  k1<<<dim3(32, 64), 256, 0, stream>>>(x, rt, hbuf);
  k2<<<dim3(32, 32), 256, 0, stream>>>(hbuf, ltw, bias, y);
}